// Round 9
// baseline (284.935 us; speedup 1.0000x reference)
//
#include <hip/hip_runtime.h>
#include <math.h>

#define D_DIM 256
#define K_NUM 4096
#define N_ROWS 32768
#define QCAP 2048
#define MARGIN 0.02f

typedef _Float16 half8 __attribute__((ext_vector_type(8)));
typedef float floatx4 __attribute__((ext_vector_type(4)));

// ---------------- vv[k] = sum_d V[d][k]^2 (r1-proven exact order) ------------
__global__ __launch_bounds__(256) void vq_vv(const float* __restrict__ V,
                                             float* __restrict__ vv) {
  int k = blockIdx.x * 256 + threadIdx.x;
  float acc = 0.0f;
  for (int d = 0; d < D_DIM; ++d) {
    float v = V[(size_t)d * K_NUM + k];
    acc = __fadd_rn(acc, __fmul_rn(v, v));
  }
  vv[k] = acc;
}

// ---- V quadrant transpose: 256 blocks of (64 cols x 64 d) -> vtb f16, vt f32
__global__ __launch_bounds__(256) void vq_prep(const float* __restrict__ V,
                                               _Float16* __restrict__ vtb,
                                               float* __restrict__ vt,
                                               int write_vt) {
  __shared__ float tile[64][64];      // [d_local][col_local] 16 KB
  const int col0 = (blockIdx.x & 63) * 64;
  const int d0 = (blockIdx.x >> 6) * 64;
  const int cq = threadIdx.x >> 6;    // 0..3
  const int cl = threadIdx.x & 63;
#pragma unroll
  for (int it = 0; it < 16; ++it) {
    int d = it * 4 + cq;
    tile[d][cl] = V[(size_t)(d0 + d) * K_NUM + col0 + cl];
  }
  __syncthreads();
#pragma unroll
  for (int qq = 0; qq < 2; ++qq) {
    int q = cq * 2 + qq;              // 0..7 local d-chunk
    half8 h;
#pragma unroll
    for (int j = 0; j < 8; ++j) h[j] = (_Float16)tile[q * 8 + j][cl];
    *(half8*)(vtb + ((size_t)(d0 / 8 + q) * K_NUM + col0 + cl) * 8) = h;
  }
  if (write_vt) {
#pragma unroll
    for (int j = 0; j < 4; ++j) {
      int d = cq * 16 + j * 4;
      float4 f;
      f.x = tile[d + 0][cl]; f.y = tile[d + 1][cl];
      f.z = tile[d + 2][cl]; f.w = tile[d + 3][cl];
      *(float4*)(vt + (size_t)(col0 + cl) * D_DIM + d0 + d) = f;
    }
  }
}

// ------------- fp16 MFMA screen, A fully in registers (32 rows/block) --------
struct alignas(16) ScreenShared {
  float vvs[K_NUM];        // 16 KB
  float xxs[32];
  float wmin[8][32];       // 1 KB
  float thr[32];
  unsigned long long best[32];   // (score_bits<<32)|col per row
  unsigned qbuf[QCAP];     // 8 KB
  int qn;
};

__device__ __forceinline__ void vq_push(ScreenShared& sh, int r, int col) {
  int u = atomicAdd(&sh.qn, 1);
  if (u < QCAP) sh.qbuf[u] = ((unsigned)r << 12) | (unsigned)col;
}

// MODE 0: fold cell mins into tb[8].  MODE 1: collect cols with s <= tb.
// A comes from registers (areg[rf][ks]); only B streams from L2 (dist-1 dbuf).
template <int MODE>
__device__ __forceinline__ void vq_cell(ScreenShared& sh,
                                        const _Float16* __restrict__ vtb,
                                        const half8 (&areg)[2][8],
                                        float* tb, int w, int l, int c) {
  const int g = l >> 4, ln = l & 15;
  const int cb = w * 512 + c * 32;
  const float vv0 = sh.vvs[cb + ln];
  const float vv1 = sh.vvs[cb + 16 + ln];
  const char* bp = (const char*)vtb + (((size_t)g * K_NUM + cb + ln) << 4);

  floatx4 acc[2][2];
#pragma unroll
  for (int rf = 0; rf < 2; ++rf)
#pragma unroll
    for (int cf = 0; cf < 2; ++cf) acc[rf][cf] = {0.f, 0.f, 0.f, 0.f};

  half8 bfb[2][2];
  bfb[0][0] = *(const half8*)bp;
  bfb[0][1] = *(const half8*)(bp + 256);

#pragma unroll
  for (int ks = 0; ks < 8; ++ks) {
    if (ks < 7) {                       // B prefetch distance 1
      const int koff = (ks + 1) * 262144;   // 4 d-rows * 4096 cols * 16 B
      bfb[(ks + 1) & 1][0] = *(const half8*)(bp + koff);
      bfb[(ks + 1) & 1][1] = *(const half8*)(bp + koff + 256);
    }
    __builtin_amdgcn_s_setprio(1);
#pragma unroll
    for (int rf = 0; rf < 2; ++rf)
#pragma unroll
      for (int cf = 0; cf < 2; ++cf)
        acc[rf][cf] = __builtin_amdgcn_mfma_f32_16x16x32_f16(
            areg[rf][ks], bfb[ks & 1][cf], acc[rf][cf], 0, 0, 0);
    __builtin_amdgcn_s_setprio(0);
  }

#pragma unroll
  for (int rf = 0; rf < 2; ++rf) {
#pragma unroll
    for (int reg = 0; reg < 4; ++reg) {
      float s0v = fmaf(-2.0f, acc[rf][0][reg], vv0);
      float s1v = fmaf(-2.0f, acc[rf][1][reg], vv1);
      float m = fminf(s0v, s1v);
      if (MODE == 0) {
        tb[rf * 4 + reg] = fminf(tb[rf * 4 + reg], m);
      } else {
        float thr = tb[rf * 4 + reg];
        if (m <= thr) {                  // rare: exec-masked push
          const int r = rf * 16 + g * 4 + reg;
          if (s0v <= thr) vq_push(sh, r, cb + ln);
          if (s1v <= thr) vq_push(sh, r, cb + 16 + ln);
        }
      }
    }
  }
}

__global__ __launch_bounds__(512, 2) void vq_screen(
    const float* __restrict__ X, const float* __restrict__ V,
    const _Float16* __restrict__ vtb, const float* __restrict__ vvp,
    const float* __restrict__ vt, float* __restrict__ idx_out,
    float* __restrict__ outq, float* __restrict__ loss_sum) {
  __shared__ ScreenShared sh;
  const int tid = threadIdx.x;
  const int w = tid >> 6, l = tid & 63;
  const int g = l >> 4, ln = l & 15;
  const int row0 = blockIdx.x * 32;

  // A fragments straight into registers (same d-map + f16 casts as r6 staging:
  // frag (rf,ks) = row rf*16+ln, d = (ks*4+g)*8 .. +7  -> bit-identical frags)
  half8 areg[2][8];
#pragma unroll
  for (int rf = 0; rf < 2; ++rf) {
#pragma unroll
    for (int ks = 0; ks < 8; ++ks) {
      const float* xp =
          X + (size_t)(row0 + rf * 16 + ln) * D_DIM + (ks * 4 + g) * 8;
      float4 v0 = *(const float4*)xp, v1 = *(const float4*)(xp + 4);
      half8 h;
      h[0] = (_Float16)v0.x; h[1] = (_Float16)v0.y;
      h[2] = (_Float16)v0.z; h[3] = (_Float16)v0.w;
      h[4] = (_Float16)v1.x; h[5] = (_Float16)v1.y;
      h[6] = (_Float16)v1.z; h[7] = (_Float16)v1.w;
      areg[rf][ks] = h;
    }
  }

#pragma unroll
  for (int it = 0; it < 8; ++it) sh.vvs[it * 512 + tid] = vvp[it * 512 + tid];

  // exact numpy-pairwise ||x||^2, wave-parallel (r6-proven, bit-exact):
  // 16 lanes per row; shfl tree == ((r0+r1)+(r2+r3))+((r4+r5)+(r6+r7)), halves
  {
    const int r = tid >> 4;              // 0..31
    const int hv = (l >> 3) & 1, j = l & 7;
    const float* p = X + (size_t)(row0 + r) * D_DIM + hv * 128 + j;
    float v = p[0];
    float acc = __fmul_rn(v, v);
#pragma unroll
    for (int i = 1; i < 16; ++i) {
      v = p[i * 8];
      acc = __fadd_rn(acc, __fmul_rn(v, v));
    }
    acc = __fadd_rn(acc, __shfl_xor(acc, 1));
    acc = __fadd_rn(acc, __shfl_xor(acc, 2));
    acc = __fadd_rn(acc, __shfl_xor(acc, 4));
    acc = __fadd_rn(acc, __shfl_xor(acc, 8));
    if ((l & 15) == 0) sh.xxs[r] = acc;
  }
  if (tid < 32) sh.best[tid] = 0xFFFFFFFFFFFFFFFFull;
  if (tid == 0) sh.qn = 0;
  __syncthreads();

  float tb[8];
#pragma unroll
  for (int i = 0; i < 8; ++i) tb[i] = INFINITY;

  // pass0: subsampled threshold (cells 0 and 8 -> same 512 cols/row as r6)
  vq_cell<0>(sh, vtb, areg, tb, w, l, 0);
  vq_cell<0>(sh, vtb, areg, tb, w, l, 8);

#pragma unroll
  for (int i = 0; i < 8; ++i) {
#pragma unroll
    for (int off = 1; off <= 8; off <<= 1)
      tb[i] = fminf(tb[i], __shfl_xor(tb[i], off));
  }
  if (ln == 0) {
#pragma unroll
    for (int rf = 0; rf < 2; ++rf)
#pragma unroll
      for (int reg = 0; reg < 4; ++reg)
        sh.wmin[w][rf * 16 + g * 4 + reg] = tb[rf * 4 + reg];
  }
  __syncthreads();
  if (tid < 32) {
    float m = sh.wmin[0][tid];
#pragma unroll
    for (int j = 1; j < 8; ++j) m = fminf(m, sh.wmin[j][tid]);
    sh.thr[tid] = m + MARGIN;
  }
  __syncthreads();
#pragma unroll
  for (int rf = 0; rf < 2; ++rf)
#pragma unroll
    for (int reg = 0; reg < 4; ++reg)
      tb[rf * 4 + reg] = sh.thr[rf * 16 + g * 4 + reg];

  // single full sweep, fixed threshold, collect candidates
  for (int c = 0; c < 16; ++c) vq_cell<1>(sh, vtb, areg, tb, w, l, c);
  __syncthreads();

  // exact fp32 rescore (same fma/shfl order as r2-r6-proven rescore)
  const int nq = min(sh.qn, QCAP);
  for (int i = w; i < nq; i += 8) {
    unsigned e = sh.qbuf[i];
    int r = (int)(e >> 12), col = (int)(e & 4095);
    float4 xv = *(const float4*)(X + (size_t)(row0 + r) * D_DIM + l * 4);
    float p = 0.f;
    if (vt) {
      float4 qv = *(const float4*)(vt + (size_t)col * D_DIM + l * 4);
      p = fmaf(xv.x, qv.x, p);
      p = fmaf(xv.y, qv.y, p);
      p = fmaf(xv.z, qv.z, p);
      p = fmaf(xv.w, qv.w, p);
    } else {
      const float* vp = V + col;
      p = fmaf(xv.x, vp[(size_t)(l * 4 + 0) * K_NUM], p);
      p = fmaf(xv.y, vp[(size_t)(l * 4 + 1) * K_NUM], p);
      p = fmaf(xv.z, vp[(size_t)(l * 4 + 2) * K_NUM], p);
      p = fmaf(xv.w, vp[(size_t)(l * 4 + 3) * K_NUM], p);
    }
#pragma unroll
    for (int off = 1; off < 64; off <<= 1) p += __shfl_xor(p, off);
    if (l == 0) {
      float s = __fadd_rn(__fsub_rn(sh.xxs[r], __fmul_rn(2.0f, p)),
                          sh.vvs[col]);
      unsigned long long key =
          ((unsigned long long)__float_as_uint(s) << 32) | (unsigned)col;
      atomicMin(&sh.best[r], key);
    }
  }
  __syncthreads();

  if (tid < 32)
    idx_out[row0 + tid] = (float)(unsigned)(sh.best[tid] & 0xFFFFFFFFu);

  // ---- fused gather + STE + loss (per-element ops identical to r2-r6) ------
  float lsum = 0.f;
#pragma unroll
  for (int it = 0; it < 4; ++it) {
    int t = it * 512 + tid;            // float4 units over 32 rows x 64
    int rloc = t >> 6;
    int c4 = (t & 63) << 2;
    int bi = (int)(unsigned)(sh.best[rloc] & 0xFFFFFFFFu);
    float4 xv = *(const float4*)(X + (size_t)(row0 + rloc) * D_DIM + c4);
    float4 qv;
    if (vt) {
      qv = *(const float4*)(vt + (size_t)bi * D_DIM + c4);
    } else {
      qv.x = V[(size_t)(c4 + 0) * K_NUM + bi];
      qv.y = V[(size_t)(c4 + 1) * K_NUM + bi];
      qv.z = V[(size_t)(c4 + 2) * K_NUM + bi];
      qv.w = V[(size_t)(c4 + 3) * K_NUM + bi];
    }
    floatx4 o;
    o[0] = __fadd_rn(xv.x, __fsub_rn(qv.x, xv.x));
    o[1] = __fadd_rn(xv.y, __fsub_rn(qv.y, xv.y));
    o[2] = __fadd_rn(xv.z, __fsub_rn(qv.z, xv.z));
    o[3] = __fadd_rn(xv.w, __fsub_rn(qv.w, xv.w));
    __builtin_nontemporal_store(
        o, (floatx4*)(outq + (size_t)(row0 + rloc) * D_DIM + c4));
    float d0 = __fsub_rn(xv.x, qv.x), d1 = __fsub_rn(xv.y, qv.y);
    float d2 = __fsub_rn(xv.z, qv.z), d3 = __fsub_rn(xv.w, qv.w);
    lsum += d0 * d0 + d1 * d1 + d2 * d2 + d3 * d3;
  }
#pragma unroll
  for (int off = 1; off < 64; off <<= 1) lsum += __shfl_xor(lsum, off);
  __syncthreads();                     // qbuf no longer needed -> reuse as red
  float* red = (float*)sh.qbuf;
  if (l == 0) red[w] = lsum;
  __syncthreads();
  if (tid == 0) {
    float s = red[0];
#pragma unroll
    for (int j = 1; j < 8; ++j) s += red[j];
    atomicAdd(loss_sum, s);
  }
}

__global__ void vq_fin(const float* __restrict__ loss_sum,
                       float* __restrict__ out_losses) {
  float m = loss_sum[0] / 8388608.0f;
  out_losses[0] = m;
  out_losses[1] = m;
}

extern "C" void kernel_launch(void* const* d_in, const int* in_sizes, int n_in,
                              void* d_out, int out_size, void* d_ws, size_t ws_size,
                              hipStream_t stream) {
  const float* x = (const float*)d_in[0];
  const float* V = (const float*)d_in[1];
  float* out = (float*)d_out;
  float* outq    = out;
  float* outloss = out + 8388608;
  float* outidx  = out + 8388610;

  float* ws_vv  = (float*)d_ws;                          // 16 KB
  float* ws_sum = ws_vv + K_NUM;                         // 4 B
  _Float16* ws_vtb = (_Float16*)((char*)d_ws + 163840);  // 2 MB
  float* ws_vt = (float*)((char*)d_ws + 163840 + 2097152);  // 4 MB
  const int have_vt = (ws_size >= (size_t)(163840 + 2097152 + 4194304));
  float* vt_arg = have_vt ? ws_vt : (float*)nullptr;

  hipMemsetAsync(ws_sum, 0, sizeof(float), stream);
  vq_vv    <<<K_NUM / 256, 256, 0, stream>>>(V, ws_vv);
  vq_prep  <<<256, 256, 0, stream>>>(V, ws_vtb, ws_vt, have_vt);
  vq_screen<<<N_ROWS / 32, 512, 0, stream>>>(x, V, ws_vtb, ws_vv, vt_arg,
                                             outidx, outq, ws_sum);
  vq_fin   <<<1, 1, 0, stream>>>(ws_sum, outloss);
}

// Round 10
// 195.203 us; speedup vs baseline: 1.4597x; 1.4597x over previous
//
#include <hip/hip_runtime.h>
#include <math.h>

#define D_DIM 256
#define K_NUM 4096
#define N_ROWS 32768
#define QCAP 3072
#define MARGIN 0.02f

typedef _Float16 half8 __attribute__((ext_vector_type(8)));
typedef float floatx4 __attribute__((ext_vector_type(4)));

// ---------------- vv[k] = sum_d V[d][k]^2 (r1-proven exact order) ------------
__global__ __launch_bounds__(256) void vq_vv(const float* __restrict__ V,
                                             float* __restrict__ vv) {
  int k = blockIdx.x * 256 + threadIdx.x;
  float acc = 0.0f;
  for (int d = 0; d < D_DIM; ++d) {
    float v = V[(size_t)d * K_NUM + k];
    acc = __fadd_rn(acc, __fmul_rn(v, v));
  }
  vv[k] = acc;
}

// ---- V quadrant transpose: 256 blocks of (64 cols x 64 d) -> vtb f16, vt f32
__global__ __launch_bounds__(256) void vq_prep(const float* __restrict__ V,
                                               _Float16* __restrict__ vtb,
                                               float* __restrict__ vt,
                                               int write_vt) {
  __shared__ float tile[64][64];      // [d_local][col_local] 16 KB
  const int col0 = (blockIdx.x & 63) * 64;
  const int d0 = (blockIdx.x >> 6) * 64;
  const int cq = threadIdx.x >> 6;    // 0..3
  const int cl = threadIdx.x & 63;
#pragma unroll
  for (int it = 0; it < 16; ++it) {
    int d = it * 4 + cq;
    tile[d][cl] = V[(size_t)(d0 + d) * K_NUM + col0 + cl];
  }
  __syncthreads();
#pragma unroll
  for (int qq = 0; qq < 2; ++qq) {
    int q = cq * 2 + qq;              // 0..7 local d-chunk
    half8 h;
#pragma unroll
    for (int j = 0; j < 8; ++j) h[j] = (_Float16)tile[q * 8 + j][cl];
    *(half8*)(vtb + ((size_t)(d0 / 8 + q) * K_NUM + col0 + cl) * 8) = h;
  }
  if (write_vt) {
#pragma unroll
    for (int j = 0; j < 4; ++j) {
      int d = cq * 16 + j * 4;
      float4 f;
      f.x = tile[d + 0][cl]; f.y = tile[d + 1][cl];
      f.z = tile[d + 2][cl]; f.w = tile[d + 3][cl];
      *(float4*)(vt + (size_t)(col0 + cl) * D_DIM + d0 + d) = f;
    }
  }
}

// ---------------- fp16 MFMA screen: pass0 threshold + single collect sweep ---
struct alignas(16) ScreenShared {
  _Float16 a[64 * 256];    // 32 KB, low-bit XOR-swizzled
  float vvs[K_NUM];        // 16 KB
  float xxs[64];
  float wmin[8][64];       // 2 KB
  float thr[64];
  unsigned long long best[64];   // (score_bits<<32)|col per row
  unsigned qbuf[QCAP];     // 12 KB
  int qn;
};

__device__ __forceinline__ void vq_push(ScreenShared& sh, int r, int col) {
  int u = atomicAdd(&sh.qn, 1);
  if (u < QCAP) sh.qbuf[u] = ((unsigned)r << 12) | (unsigned)col;
}

// MODE 0: fold cell mins into tb[16].  MODE 1: collect cols with s <= tb.
// ks-pipelined: prefetch ks+1's A (LDS) and B (L2) fragments during ks's MFMAs.
// Cell-local state only (r7 lesson: cross-cell carried state spills).
template <int MODE>
__device__ __forceinline__ void vq_cell(ScreenShared& sh,
                                        const _Float16* __restrict__ vtb,
                                        float* tb, int w, int l, int c) {
  const int g = l >> 4, ln = l & 15;
  const int cb = w * 512 + c * 32;
  const float vv0 = sh.vvs[cb + ln];
  const float vv1 = sh.vvs[cb + 16 + ln];

  // A half-offset: (ln<<8) ^ (ch<<3), ch = (ks<<2) ^ g ^ (ln&7)
  const int abase = (ln << 8) ^ ((g ^ (ln & 7)) << 3);
  const char* bp = (const char*)vtb + (((size_t)g * K_NUM + cb + ln) << 4);

  floatx4 acc[4][2];
#pragma unroll
  for (int rf = 0; rf < 4; ++rf)
#pragma unroll
    for (int cf = 0; cf < 2; ++cf) acc[rf][cf] = {0.f, 0.f, 0.f, 0.f};

  half8 afb[2][4], bfb[2][2];
  // prologue: ks = 0 fragments
  bfb[0][0] = *(const half8*)bp;
  bfb[0][1] = *(const half8*)(bp + 256);
#pragma unroll
  for (int rf = 0; rf < 4; ++rf)
    afb[0][rf] = *(const half8*)(sh.a + abase + rf * 4096);

#pragma unroll
  for (int ks = 0; ks < 8; ++ks) {
    const int cur = ks & 1, nxt = cur ^ 1;   // compile-time (full unroll)
    if (ks < 7) {
      const int koff = (ks + 1) * 262144;    // 4*K_NUM*16 bytes per k-step
      bfb[nxt][0] = *(const half8*)(bp + koff);
      bfb[nxt][1] = *(const half8*)(bp + koff + 256);
      const int aoff = abase ^ ((ks + 1) << 5);
#pragma unroll
      for (int rf = 0; rf < 4; ++rf)
        afb[nxt][rf] = *(const half8*)(sh.a + aoff + rf * 4096);
    }
#pragma unroll
    for (int rf = 0; rf < 4; ++rf)
#pragma unroll
      for (int cf = 0; cf < 2; ++cf)
        acc[rf][cf] = __builtin_amdgcn_mfma_f32_16x16x32_f16(
            afb[cur][rf], bfb[cur][cf], acc[rf][cf], 0, 0, 0);
  }

#pragma unroll
  for (int rf = 0; rf < 4; ++rf) {
#pragma unroll
    for (int reg = 0; reg < 4; ++reg) {
      float s0v = fmaf(-2.0f, acc[rf][0][reg], vv0);
      float s1v = fmaf(-2.0f, acc[rf][1][reg], vv1);
      float m = fminf(s0v, s1v);
      if (MODE == 0) {
        tb[rf * 4 + reg] = fminf(tb[rf * 4 + reg], m);
      } else {
        float thr = tb[rf * 4 + reg];
        if (m <= thr) {                  // rare: exec-masked push
          const int r = rf * 16 + g * 4 + reg;
          if (s0v <= thr) vq_push(sh, r, cb + ln);
          if (s1v <= thr) vq_push(sh, r, cb + 16 + ln);
        }
      }
    }
  }
}

__global__ __launch_bounds__(512, 4) void vq_screen(
    const float* __restrict__ X, const float* __restrict__ V,
    const _Float16* __restrict__ vtb, const float* __restrict__ vvp,
    const float* __restrict__ vt, float* __restrict__ idx_out,
    float* __restrict__ outq, float* __restrict__ loss_sum) {
  __shared__ ScreenShared sh;
  const int tid = threadIdx.x;
  const int w = tid >> 6, l = tid & 63;
  const int row0 = blockIdx.x * 64;

  // stage A: f32 -> f16, low-bit XOR-swizzled
#pragma unroll
  for (int it = 0; it < 4; ++it) {
    int idx = it * 512 + tid;
    int r = idx >> 5, s = idx & 31;
    const float* xp = X + (size_t)(row0 + r) * D_DIM + s * 8;
    float4 v0 = *(const float4*)xp, v1 = *(const float4*)(xp + 4);
    half8 h;
    h[0] = (_Float16)v0.x; h[1] = (_Float16)v0.y;
    h[2] = (_Float16)v0.z; h[3] = (_Float16)v0.w;
    h[4] = (_Float16)v1.x; h[5] = (_Float16)v1.y;
    h[6] = (_Float16)v1.z; h[7] = (_Float16)v1.w;
    int slot = (r << 5) | (s ^ (r & 7));
    *(half8*)&sh.a[slot * 8] = h;
  }
#pragma unroll
  for (int it = 0; it < 8; ++it) sh.vvs[it * 512 + tid] = vvp[it * 512 + tid];

  // exact numpy-pairwise ||x||^2, wave-parallel (r6-proven, bit-exact)
  {
    const int grp = tid >> 4;            // 0..31, handles rows 2*grp, 2*grp+1
    const int hv = (l >> 3) & 1, j = l & 7;
#pragma unroll
    for (int rr = 0; rr < 2; ++rr) {
      const int r = grp * 2 + rr;
      const float* p = X + (size_t)(row0 + r) * D_DIM + hv * 128 + j;
      float v = p[0];
      float acc = __fmul_rn(v, v);
#pragma unroll
      for (int i = 1; i < 16; ++i) {
        v = p[i * 8];
        acc = __fadd_rn(acc, __fmul_rn(v, v));
      }
      acc = __fadd_rn(acc, __shfl_xor(acc, 1));
      acc = __fadd_rn(acc, __shfl_xor(acc, 2));
      acc = __fadd_rn(acc, __shfl_xor(acc, 4));
      acc = __fadd_rn(acc, __shfl_xor(acc, 8));
      if ((l & 15) == 0) sh.xxs[r] = acc;
    }
  }
  if (tid < 64) sh.best[tid] = 0xFFFFFFFFFFFFFFFFull;
  if (tid == 0) sh.qn = 0;
  __syncthreads();

  float tb[16];
#pragma unroll
  for (int i = 0; i < 16; ++i) tb[i] = INFINITY;

  // pass0: subsampled threshold (c-iters 0 and 8 -> 512 cols blockwide)
  vq_cell<0>(sh, vtb, tb, w, l, 0);
  vq_cell<0>(sh, vtb, tb, w, l, 8);

#pragma unroll
  for (int i = 0; i < 16; ++i) {
#pragma unroll
    for (int off = 1; off <= 8; off <<= 1)
      tb[i] = fminf(tb[i], __shfl_xor(tb[i], off));
  }
  {
    const int g = l >> 4, ln = l & 15;
    if (ln == 0) {
#pragma unroll
      for (int rf = 0; rf < 4; ++rf)
#pragma unroll
        for (int reg = 0; reg < 4; ++reg)
          sh.wmin[w][rf * 16 + g * 4 + reg] = tb[rf * 4 + reg];
    }
  }
  __syncthreads();
  if (tid < 64) {
    float m = sh.wmin[0][tid];
#pragma unroll
    for (int j = 1; j < 8; ++j) m = fminf(m, sh.wmin[j][tid]);
    sh.thr[tid] = m + MARGIN;
  }
  __syncthreads();
  {
    const int g = l >> 4;
#pragma unroll
    for (int rf = 0; rf < 4; ++rf)
#pragma unroll
      for (int reg = 0; reg < 4; ++reg)
        tb[rf * 4 + reg] = sh.thr[rf * 16 + g * 4 + reg];
  }

  // single full sweep, fixed threshold, collect candidates
  for (int c = 0; c < 16; ++c) vq_cell<1>(sh, vtb, tb, w, l, c);
  __syncthreads();

  // exact fp32 rescore (same fma/shfl order as r2-r6-proven rescore)
  const int nq = min(sh.qn, QCAP);
  for (int i = w; i < nq; i += 8) {
    unsigned e = sh.qbuf[i];
    int r = (int)(e >> 12), col = (int)(e & 4095);
    float4 xv = *(const float4*)(X + (size_t)(row0 + r) * D_DIM + l * 4);
    float p = 0.f;
    if (vt) {
      float4 qv = *(const float4*)(vt + (size_t)col * D_DIM + l * 4);
      p = fmaf(xv.x, qv.x, p);
      p = fmaf(xv.y, qv.y, p);
      p = fmaf(xv.z, qv.z, p);
      p = fmaf(xv.w, qv.w, p);
    } else {
      const float* vp = V + col;
      p = fmaf(xv.x, vp[(size_t)(l * 4 + 0) * K_NUM], p);
      p = fmaf(xv.y, vp[(size_t)(l * 4 + 1) * K_NUM], p);
      p = fmaf(xv.z, vp[(size_t)(l * 4 + 2) * K_NUM], p);
      p = fmaf(xv.w, vp[(size_t)(l * 4 + 3) * K_NUM], p);
    }
#pragma unroll
    for (int off = 1; off < 64; off <<= 1) p += __shfl_xor(p, off);
    if (l == 0) {
      float s = __fadd_rn(__fsub_rn(sh.xxs[r], __fmul_rn(2.0f, p)),
                          sh.vvs[col]);
      unsigned long long key =
          ((unsigned long long)__float_as_uint(s) << 32) | (unsigned)col;
      atomicMin(&sh.best[r], key);
    }
  }
  __syncthreads();

  if (tid < 64)
    idx_out[row0 + tid] = (float)(unsigned)(sh.best[tid] & 0xFFFFFFFFu);

  // ---- fused gather + STE + loss (per-element ops identical to r2-r6) ------
  // ONLY delta vs r6: outq store is non-temporal (keeps vtb L2-resident).
  float lsum = 0.f;
#pragma unroll
  for (int it = 0; it < 8; ++it) {
    int t = it * 512 + tid;            // float4 units over 64 rows x 64
    int rloc = t >> 6;
    int c4 = (t & 63) << 2;
    int bi = (int)(unsigned)(sh.best[rloc] & 0xFFFFFFFFu);
    float4 xv = *(const float4*)(X + (size_t)(row0 + rloc) * D_DIM + c4);
    float4 qv;
    if (vt) {
      qv = *(const float4*)(vt + (size_t)bi * D_DIM + c4);
    } else {
      qv.x = V[(size_t)(c4 + 0) * K_NUM + bi];
      qv.y = V[(size_t)(c4 + 1) * K_NUM + bi];
      qv.z = V[(size_t)(c4 + 2) * K_NUM + bi];
      qv.w = V[(size_t)(c4 + 3) * K_NUM + bi];
    }
    floatx4 o;
    o[0] = __fadd_rn(xv.x, __fsub_rn(qv.x, xv.x));
    o[1] = __fadd_rn(xv.y, __fsub_rn(qv.y, xv.y));
    o[2] = __fadd_rn(xv.z, __fsub_rn(qv.z, xv.z));
    o[3] = __fadd_rn(xv.w, __fsub_rn(qv.w, xv.w));
    __builtin_nontemporal_store(
        o, (floatx4*)(outq + (size_t)(row0 + rloc) * D_DIM + c4));
    float d0 = __fsub_rn(xv.x, qv.x), d1 = __fsub_rn(xv.y, qv.y);
    float d2 = __fsub_rn(xv.z, qv.z), d3 = __fsub_rn(xv.w, qv.w);
    lsum += d0 * d0 + d1 * d1 + d2 * d2 + d3 * d3;
  }
#pragma unroll
  for (int off = 1; off < 64; off <<= 1) lsum += __shfl_xor(lsum, off);
  __syncthreads();                     // qbuf no longer needed -> reuse as red
  float* red = (float*)sh.qbuf;
  if (l == 0) red[w] = lsum;
  __syncthreads();
  if (tid == 0) {
    float s = red[0];
#pragma unroll
    for (int j = 1; j < 8; ++j) s += red[j];
    atomicAdd(loss_sum, s);
  }
}

__global__ void vq_fin(const float* __restrict__ loss_sum,
                       float* __restrict__ out_losses) {
  float m = loss_sum[0] / 8388608.0f;
  out_losses[0] = m;
  out_losses[1] = m;
}

extern "C" void kernel_launch(void* const* d_in, const int* in_sizes, int n_in,
                              void* d_out, int out_size, void* d_ws, size_t ws_size,
                              hipStream_t stream) {
  const float* x = (const float*)d_in[0];
  const float* V = (const float*)d_in[1];
  float* out = (float*)d_out;
  float* outq    = out;
  float* outloss = out + 8388608;
  float* outidx  = out + 8388610;

  float* ws_vv  = (float*)d_ws;                          // 16 KB
  float* ws_sum = ws_vv + K_NUM;                         // 4 B
  _Float16* ws_vtb = (_Float16*)((char*)d_ws + 163840);  // 2 MB
  float* ws_vt = (float*)((char*)d_ws + 163840 + 2097152);  // 4 MB
  const int have_vt = (ws_size >= (size_t)(163840 + 2097152 + 4194304));
  float* vt_arg = have_vt ? ws_vt : (float*)nullptr;

  hipMemsetAsync(ws_sum, 0, sizeof(float), stream);
  vq_vv    <<<K_NUM / 256, 256, 0, stream>>>(V, ws_vv);
  vq_prep  <<<256, 256, 0, stream>>>(V, ws_vtb, ws_vt, have_vt);
  vq_screen<<<N_ROWS / 64, 512, 0, stream>>>(x, V, ws_vtb, ws_vv, vt_arg,
                                             outidx, outq, ws_sum);
  vq_fin   <<<1, 1, 0, stream>>>(ws_sum, outloss);
}